// Round 9
// baseline (369.293 us; speedup 1.0000x reference)
//
#include <hip/hip_runtime.h>

// Problem constants (B=8, T=2048, C=1024, H=64)
#define TB 2048
#define NB 8
#define CEMB 1024
#define HD 64
#define BT (NB*TB)
// Q pre-scale: 1/sqrt(1024) * log2(e) — softmax in exp2 domain, no online max
#define QSCALE 0.04508422f

typedef __attribute__((ext_vector_type(8))) short bf16x8;
typedef __attribute__((ext_vector_type(4))) short bf16x4;
typedef __attribute__((ext_vector_type(4))) float f32x4;

#define MFMA32(a, b, c) __builtin_amdgcn_mfma_f32_16x16x32_bf16(a, b, c, 0, 0, 0)
#define MFMA16(a, b, c) __builtin_amdgcn_mfma_f32_16x16x16bf16_1k(a, b, c, 0, 0, 0)

__device__ inline short f2bf(float f) {
    union { float f; unsigned u; } v; v.f = f;
    unsigned r = v.u + 0x7fffu + ((v.u >> 16) & 1u);   // RNE
    return (short)(r >> 16);
}
__device__ inline unsigned cvt_pk_bf16(float a, float b) {
    unsigned r;
    asm("v_cvt_pk_bf16_f32 %0, %1, %2" : "=v"(r) : "v"(a), "v"(b));
    return r;
}
__device__ inline bf16x4 pack2(unsigned w0, unsigned w1) {
    union { unsigned u[2]; bf16x4 v; } c; c.u[0] = w0; c.u[1] = w1; return c.v;
}
__device__ inline bf16x8 pack4(unsigned w0, unsigned w1, unsigned w2, unsigned w3) {
    union { unsigned u[4]; bf16x8 v; } c;
    c.u[0] = w0; c.u[1] = w1; c.u[2] = w2; c.u[3] = w3; return c.v;
}
__device__ inline void gload_lds16(const void* g, void* l) {
    __builtin_amdgcn_global_load_lds((const __attribute__((address_space(1))) void*)g,
                                     (__attribute__((address_space(3))) void*)l, 16, 0, 0);
}

// grid-wide barrier (cooperative-groups pattern; monotone counter, memset-0 per launch)
__device__ inline void gsync(unsigned* bar, unsigned nb) {
    __syncthreads();
    if (threadIdx.x == 0) {
        __threadfence();                                       // release our global writes
        unsigned old = __hip_atomic_fetch_add(bar, 1u, __ATOMIC_ACQ_REL,
                                              __HIP_MEMORY_SCOPE_AGENT);
        unsigned tgt = (old / nb + 1u) * nb;
        while (__hip_atomic_load(bar, __ATOMIC_ACQUIRE, __HIP_MEMORY_SCOPE_AGENT) < tgt)
            __builtin_amdgcn_s_sleep(2);
    }
    __syncthreads();
    __threadfence();                                           // acquire: drop stale caches
}

union SMem {
    struct { char xb[2][4096]; char wb[2][12288]; } q;   // qkv: 32 KB
    struct { float Of[4][2][16][68]; float Ml[4][2][16]; } f; // flash: 35.3 KB
};

// ---------- fused: P0 wpack -> gsync -> P1 qkv -> gsync -> P2 flash ----------
// R7 post-mortem: qkv_mm ~30us on pre-converted L3-resident bf16 (6250 cyc/iter
// vs <1K model) -> no intra-kernel model fits; suspicion moved to inter-dispatch
// fixed cost (R6->R7: +1 dispatch = +10us). R8 fuses all compute into ONE
// dispatch via software grid sync. Co-residency: LDS 35.3KB -> >=3 blk/CU
// capacity (768) >= grid 512; VGPR<=168 via lb(256,3). Fused dur also exceeds
// the 41us fill cutoff -> full-path counters finally visible.
__global__ __launch_bounds__(256, 3) void fused(const float* __restrict__ x,
                                                const float* __restrict__ Wk,
                                                const float* __restrict__ Wq,
                                                const float* __restrict__ Wv,
                                                short* __restrict__ W2,
                                                short* __restrict__ Qb,
                                                short* __restrict__ Kb,
                                                short* __restrict__ Vt,
                                                float* __restrict__ out,
                                                unsigned* __restrict__ bar) {
    __shared__ __align__(16) SMem sm;
    int tid = threadIdx.x;

    // ================= P0: wpack (blocks 0..95) / x L2-prefetch (others) ======
    if (blockIdx.x < 96) {
        int c = blockIdx.x * 256 + tid;
        int lane = c & 63, ntk = c >> 6;
        int nt = ntk % 12, kc = ntk / 12;
        int n = nt * 16 + (lane & 15);
        int col = kc * 32 + (lane >> 4) * 8;
        const float* src = (n < 64) ? Wk + n * 1024
                         : (n < 128) ? Wq + (n - 64) * 1024
                                     : Wv + (n - 128) * 1024;
        float4 a = *(const float4*)(src + col);
        float4 b = *(const float4*)(src + col + 4);
        bf16x8 o;
        o[0] = f2bf(a.x); o[1] = f2bf(a.y); o[2] = f2bf(a.z); o[3] = f2bf(a.w);
        o[4] = f2bf(b.x); o[5] = f2bf(b.y); o[6] = f2bf(b.z); o[7] = f2bf(b.w);
        *(bf16x8*)(W2 + (size_t)c * 8) = o;
    } else {
        // warm L2/L3 with this block's x rows (32 rows x 4KB), 1 touch / 64B
        const float* xp = x + (size_t)blockIdx.x * 32 * CEMB;
        float s = 0.f;
#pragma unroll
        for (int k = 0; k < 8; ++k) s += xp[tid * 16 + k * 4096];
        asm volatile("" :: "v"(s));                   // keep loads live (rule #17)
    }
    gsync(bar, 512);

    // ================= P1: QKV GEMM — 32 rows/block, BK=32, dual-staged =======
    {
        int wid = tid >> 6, lane = tid & 63;
        int l15 = lane & 15, quad = lane >> 4;
        int mgrp = wid >> 1, ngrp = wid & 1;          // 2 m-tiles x 2 n-groups
        int m0 = blockIdx.x * 32;

        f32x4 acc[6];
#pragma unroll
        for (int j = 0; j < 6; ++j) acc[j] = f32x4{0.f, 0.f, 0.f, 0.f};

        // x stage (1 instr/wave/t): rows wid*8..+7, source pre-swizzled (G21)
        int rl = lane >> 3;                           // row-in-group 0..7
        const char* xsrc = (const char*)x + ((size_t)(m0 + wid * 8 + rl) << 12)
                         + (((lane & 7) * 16) ^ ((rl & 7) << 4));
        // W2 stage (3 instr/wave/t): nt slices wid*3..+2 of kc=t (12KB/t), linear
        const char* wsrc = (const char*)W2 + (size_t)(wid * 3) * 1024 + lane * 16;

#define STG(bsel, t) do { \
        gload_lds16(wsrc + (size_t)(t) * 12288,        &sm.q.wb[bsel][wid * 3072]);        \
        gload_lds16(wsrc + (size_t)(t) * 12288 + 1024, &sm.q.wb[bsel][wid * 3072 + 1024]); \
        gload_lds16(wsrc + (size_t)(t) * 12288 + 2048, &sm.q.wb[bsel][wid * 3072 + 2048]); \
        gload_lds16(xsrc + (t) * 128, &sm.q.xb[bsel][wid * 1024]); } while (0)

        STG(0, 0);
        int arow = mgrp * 16 + l15;
        int sca = (quad * 32)      ^ ((arow & 7) << 4);
        int scb = (quad * 32 + 16) ^ ((arow & 7) << 4);
        const char* wn0 = (const char*)&sm.q.wb[0][0] + (size_t)(ngrp * 6) * 1024 + lane * 16;

        for (int t = 0; t < 32; ++t) {
            if (t < 31) {
                STG((t + 1) & 1, t + 1);
                asm volatile("s_waitcnt vmcnt(4)" ::: "memory");   // drain stage(t) only
            } else {
                asm volatile("s_waitcnt vmcnt(0)" ::: "memory");
            }
            __builtin_amdgcn_s_barrier();             // buf[t&1] staged for all waves

            const char* xbp = &sm.q.xb[t & 1][0];
            const char* wn  = wn0 + (t & 1) * 12288;
            float4 a0 = *(const float4*)(xbp + arow * 128 + sca);
            float4 a1 = *(const float4*)(xbp + arow * 128 + scb);
            bf16x8 af = pack4(cvt_pk_bf16(a0.x, a0.y), cvt_pk_bf16(a0.z, a0.w),
                              cvt_pk_bf16(a1.x, a1.y), cvt_pk_bf16(a1.z, a1.w));
#pragma unroll
            for (int j = 0; j < 6; ++j) {
                bf16x8 wf = *(const bf16x8*)(wn + j * 1024);
                acc[j] = MFMA32(af, wf, acc[j]);
            }
            __builtin_amdgcn_s_barrier();             // reads done -> re-stageable
        }
#undef STG

        // epilogue: direct stores (mapping verified vs flash consumption)
        int bb = blockIdx.x >> 6, sblk32 = blockIdx.x & 63;
#pragma unroll
        for (int j = 0; j < 6; ++j) {
            int gnt = ngrp * 6 + j;                   // wave-uniform
            f32x4 s0 = acc[j];
            int row0 = m0 + mgrp * 16 + quad * 4;
            if (gnt < 4) {                            // K rows [m][h]
                int h = gnt * 16 + l15;
#pragma unroll
                for (int r = 0; r < 4; ++r)
                    Kb[(size_t)(row0 + r) * HD + h] = f2bf(s0[r]);
            } else if (gnt < 8) {                     // Q rows, pre-scaled
                int h = (gnt - 4) * 16 + l15;
#pragma unroll
                for (int r = 0; r < 4; ++r)
                    Qb[(size_t)(row0 + r) * HD + h] = f2bf(s0[r] * QSCALE);
            } else {                                  // V: pos = quad*8 + mgrp*4 + r
                int h = (gnt - 8) * 16 + l15;
                uint2 v2;
                v2.x = cvt_pk_bf16(s0[0], s0[1]);
                v2.y = cvt_pk_bf16(s0[2], s0[3]);
                *(uint2*)(Vt + ((size_t)((bb * 64 + sblk32) * 64 + h)) * 32
                             + quad * 8 + mgrp * 4) = v2;
            }
        }
    }
    gsync(bar, 512);

    // ================= P2: causal flash (identical structure, union LDS) ======
    {
        int wave = tid >> 6, lane = tid & 63;
        int l15 = lane & 15, quad = lane >> 4;
        int i = blockIdx.x;
        int round = i >> 8, s = i & 255;
        int b = s & 7;
        int g32 = s >> 3;
        int q32 = round ? 63 - g32 : g32;
        int tq0 = q32 * 32;
        size_t bT = (size_t)b * TB;

        const short* qr0 = Qb + (bT + tq0 + l15) * HD;
        const short* qr1 = Qb + (bT + tq0 + 16 + l15) * HD;
        bf16x8 qf00 = *(const bf16x8*)(qr0 + quad * 8);
        bf16x8 qf01 = *(const bf16x8*)(qr0 + 32 + quad * 8);
        bf16x8 qf10 = *(const bf16x8*)(qr1 + quad * 8);
        bf16x8 qf11 = *(const bf16x8*)(qr1 + 32 + quad * 8);

        bf16x4 ones4;
#pragma unroll
        for (int j = 0; j < 4; ++j) ones4[j] = (short)0x3F80;

        f32x4 accO0[4], accO1[4];
#pragma unroll
        for (int k = 0; k < 4; ++k) { accO0[k] = f32x4{0.f,0.f,0.f,0.f}; accO1[k] = f32x4{0.f,0.f,0.f,0.f}; }
        f32x4 accL0 = f32x4{0.f,0.f,0.f,0.f}, accL1 = f32x4{0.f,0.f,0.f,0.f};

        int ntiles = (tq0 + 95) >> 6;
        const short* kbase = Kb + bT * HD;
        const short* vtb = Vt + (size_t)b * 131072;

        int myt = wave;
        if (myt < ntiles) {
            bf16x8 kf[8];
            {
                const short* kr = kbase + (size_t)(myt * 64 + l15) * HD + quad * 8;
#pragma unroll
                for (int st = 0; st < 4; ++st) {
                    kf[st * 2]     = *(const bf16x8*)(kr + (size_t)st * 16 * HD);
                    kf[st * 2 + 1] = *(const bf16x8*)(kr + (size_t)st * 16 * HD + 32);
                }
            }
            for (; myt < ntiles; myt += 4) {
                int s0 = myt * 64;
                bf16x8 vf8[8];
#pragma unroll
                for (int sb2 = 0; sb2 < 2; ++sb2)
#pragma unroll
                    for (int ht = 0; ht < 4; ++ht)
                        vf8[sb2 * 4 + ht] = *(const bf16x8*)(
                            vtb + ((size_t)(((s0 >> 5) + sb2) * 64 + ht * 16 + l15)) * 32 + quad * 8);
                f32x4 sv0[4], sv1[4];
                __builtin_amdgcn_s_setprio(1);
#pragma unroll
                for (int st = 0; st < 4; ++st) {
                    f32x4 t0 = f32x4{0.f,0.f,0.f,0.f}, t1 = f32x4{0.f,0.f,0.f,0.f};
                    t0 = MFMA32(kf[st * 2], qf00, t0);
                    t0 = MFMA32(kf[st * 2 + 1], qf01, t0);
                    t1 = MFMA32(kf[st * 2], qf10, t1);
                    t1 = MFMA32(kf[st * 2 + 1], qf11, t1);
                    sv0[st] = t0; sv1[st] = t1;
                }
                __builtin_amdgcn_s_setprio(0);
                if (myt + 4 < ntiles) {
                    const short* kr = kbase + (size_t)(s0 + 256 + l15) * HD + quad * 8;
#pragma unroll
                    for (int st = 0; st < 4; ++st) {
                        kf[st * 2]     = *(const bf16x8*)(kr + (size_t)st * 16 * HD);
                        kf[st * 2 + 1] = *(const bf16x8*)(kr + (size_t)st * 16 * HD + 32);
                    }
                }
                bf16x4 pk0[4], pk1[4];
                if (s0 + 63 <= tq0) {
#pragma unroll
                    for (int st = 0; st < 4; ++st) {
                        unsigned w00 = cvt_pk_bf16(__builtin_amdgcn_exp2f(sv0[st][0]),
                                                   __builtin_amdgcn_exp2f(sv0[st][1]));
                        unsigned w01 = cvt_pk_bf16(__builtin_amdgcn_exp2f(sv0[st][2]),
                                                   __builtin_amdgcn_exp2f(sv0[st][3]));
                        unsigned w10 = cvt_pk_bf16(__builtin_amdgcn_exp2f(sv1[st][0]),
                                                   __builtin_amdgcn_exp2f(sv1[st][1]));
                        unsigned w11 = cvt_pk_bf16(__builtin_amdgcn_exp2f(sv1[st][2]),
                                                   __builtin_amdgcn_exp2f(sv1[st][3]));
                        pk0[st] = pack2(w00, w01);
                        pk1[st] = pack2(w10, w11);
                    }
                } else {
                    int t0g = tq0 + l15, t1g = tq0 + 16 + l15;
#pragma unroll
                    for (int st = 0; st < 4; ++st) {
                        bool full0 = (s0 + st * 16 + 15 <= tq0);
                        bool full1 = (s0 + st * 16 + 15 <= tq0 + 16);
                        int sb = s0 + st * 16 + quad * 4;
                        float a0 = (full0 || sb + 0 <= t0g) ? __builtin_amdgcn_exp2f(sv0[st][0]) : 0.f;
                        float a1 = (full0 || sb + 1 <= t0g) ? __builtin_amdgcn_exp2f(sv0[st][1]) : 0.f;
                        float a2 = (full0 || sb + 2 <= t0g) ? __builtin_amdgcn_exp2f(sv0[st][2]) : 0.f;
                        float a3 = (full0 || sb + 3 <= t0g) ? __builtin_amdgcn_exp2f(sv0[st][3]) : 0.f;
                        float c0 = (full1 || sb + 0 <= t1g) ? __builtin_amdgcn_exp2f(sv1[st][0]) : 0.f;
                        float c1 = (full1 || sb + 1 <= t1g) ? __builtin_amdgcn_exp2f(sv1[st][1]) : 0.f;
                        float c2 = (full1 || sb + 2 <= t1g) ? __builtin_amdgcn_exp2f(sv1[st][2]) : 0.f;
                        float c3 = (full1 || sb + 3 <= t1g) ? __builtin_amdgcn_exp2f(sv1[st][3]) : 0.f;
                        pk0[st] = pack2(cvt_pk_bf16(a0, a1), cvt_pk_bf16(a2, a3));
                        pk1[st] = pack2(cvt_pk_bf16(c0, c1), cvt_pk_bf16(c2, c3));
                    }
                }
                __builtin_amdgcn_s_setprio(1);
#pragma unroll
                for (int g = 0; g < 4; ++g) {
                    accL0 = MFMA16(ones4, pk0[g], accL0);
                    accL1 = MFMA16(ones4, pk1[g], accL1);
#pragma unroll
                    for (int ht = 0; ht < 4; ++ht) {
                        bf16x8 v = vf8[(g >> 1) * 4 + ht];
                        bf16x4 va;
                        if (g & 1) { va[0] = v[4]; va[1] = v[5]; va[2] = v[6]; va[3] = v[7]; }
                        else       { va[0] = v[0]; va[1] = v[1]; va[2] = v[2]; va[3] = v[3]; }
                        accO0[ht] = MFMA16(va, pk0[g], accO0[ht]);
                        accO1[ht] = MFMA16(va, pk1[g], accO1[ht]);
                    }
                }
                __builtin_amdgcn_s_setprio(0);
            }
        }

#pragma unroll
        for (int ht = 0; ht < 4; ++ht) {
            float4 o0, o1;
            o0.x = accO0[ht][0]; o0.y = accO0[ht][1]; o0.z = accO0[ht][2]; o0.w = accO0[ht][3];
            o1.x = accO1[ht][0]; o1.y = accO1[ht][1]; o1.z = accO1[ht][2]; o1.w = accO1[ht][3];
            *(float4*)&sm.f.Of[wave][0][l15][ht * 16 + quad * 4] = o0;
            *(float4*)&sm.f.Of[wave][1][l15][ht * 16 + quad * 4] = o1;
        }
        if (quad == 0) { sm.f.Ml[wave][0][l15] = accL0[0]; sm.f.Ml[wave][1][l15] = accL1[0]; }
        __syncthreads();

        int row = tid >> 4, c4 = (tid & 15) * 4;
#pragma unroll
        for (int qt = 0; qt < 2; ++qt) {
            float L = sm.f.Ml[0][qt][row] + sm.f.Ml[1][qt][row] + sm.f.Ml[2][qt][row] + sm.f.Ml[3][qt][row];
            float inv = 1.0f / L;
            float4 p0 = *(const float4*)&sm.f.Of[0][qt][row][c4];
            float4 p1 = *(const float4*)&sm.f.Of[1][qt][row][c4];
            float4 p2 = *(const float4*)&sm.f.Of[2][qt][row][c4];
            float4 p3 = *(const float4*)&sm.f.Of[3][qt][row][c4];
            float4 o;
            o.x = (p0.x + p1.x + p2.x + p3.x) * inv;
            o.y = (p0.y + p1.y + p2.y + p3.y) * inv;
            o.z = (p0.z + p1.z + p2.z + p3.z) * inv;
            o.w = (p0.w + p1.w + p2.w + p3.w) * inv;
            *(float4*)(out + (bT + tq0 + qt * 16 + row) * HD + c4) = o;
        }
    }
}

extern "C" void kernel_launch(void* const* d_in, const int* in_sizes, int n_in,
                              void* d_out, int out_size, void* d_ws, size_t ws_size,
                              hipStream_t stream) {
    const float* x  = (const float*)d_in[0];
    const float* Wk = (const float*)d_in[1];
    const float* Wq = (const float*)d_in[2];
    const float* Wv = (const float*)d_in[3];
    float* out = (float*)d_out;

    short* W2 = (short*)d_ws;                // 192*1024 bf16 (frag-packed)
    short* Qb = W2 + 192 * 1024;             // [BT][64], pre-scaled
    short* Kb = Qb + (size_t)BT * HD;        // [BT][64]
    short* Vt = Kb + (size_t)BT * HD;        // [B][64 sblk32][64 h][32]
    unsigned* bar = (unsigned*)((char*)d_ws + (16u << 20));  // far from buffers

    hipMemsetAsync(bar, 0, 16, stream);      // barrier init (ws re-poisoned per iter)
    fused<<<512, 256, 0, stream>>>(x, Wk, Wq, Wv, W2, Qb, Kb, Vt, out, bar);
}

// Round 12
// 131.474 us; speedup vs baseline: 2.8089x; 2.8089x over previous
//
#include <hip/hip_runtime.h>

// Problem constants (B=8, T=2048, C=1024, H=64)
#define TB 2048
#define NB 8
#define CEMB 1024
#define HD 64
#define BT (NB*TB)
// Q pre-scale: 1/sqrt(1024) * log2(e) — softmax in exp2 domain, no online max
#define QSCALE 0.04508422f

typedef __attribute__((ext_vector_type(8))) short bf16x8;
typedef __attribute__((ext_vector_type(4))) short bf16x4;
typedef __attribute__((ext_vector_type(4))) float f32x4;

#define MFMA32(a, b, c) __builtin_amdgcn_mfma_f32_16x16x32_bf16(a, b, c, 0, 0, 0)
// no __has_builtin guard — returns false on the HOST pass (R8 failure)
#define MFMA16(a, b, c) __builtin_amdgcn_mfma_f32_16x16x16bf16_1k(a, b, c, 0, 0, 0)

__device__ inline short f2bf(float f) {
    union { float f; unsigned u; } v; v.f = f;
    unsigned r = v.u + 0x7fffu + ((v.u >> 16) & 1u);   // RNE
    return (short)(r >> 16);
}
__device__ inline float bf2f(short s) {
    union { unsigned u; float f; } v; v.u = ((unsigned)(unsigned short)s) << 16;
    return v.f;
}
// HW packed f32->bf16 RNE: 1 op per pair
__device__ inline unsigned cvt_pk_bf16(float a, float b) {
    unsigned r;
    asm("v_cvt_pk_bf16_f32 %0, %1, %2" : "=v"(r) : "v"(a), "v"(b));
    return r;
}
__device__ inline bf16x4 pack2(unsigned w0, unsigned w1) {
    union { unsigned u[2]; bf16x4 v; } c; c.u[0] = w0; c.u[1] = w1; return c.v;
}
__device__ inline bf16x8 pack4(unsigned w0, unsigned w1, unsigned w2, unsigned w3) {
    union { unsigned u[4]; bf16x8 v; } c;
    c.u[0] = w0; c.u[1] = w1; c.u[2] = w2; c.u[3] = w3; return c.v;
}
// async global->LDS 16B (dest = wave-uniform base + lane*16; src per-lane)
__device__ inline void gload_lds16(const void* g, void* l) {
    __builtin_amdgcn_global_load_lds((const __attribute__((address_space(1))) void*)g,
                                     (__attribute__((address_space(3))) void*)l, 16, 0, 0);
}

// ---------- K1: pack [Wk;Wq;Wv] into MFMA B-frag order, bf16 ----------
__global__ __launch_bounds__(256) void wpack(const float* __restrict__ Wk,
                                             const float* __restrict__ Wq,
                                             const float* __restrict__ Wv,
                                             short* __restrict__ W2) {
    int c = blockIdx.x * 256 + threadIdx.x;          // 96 blocks
    int lane = c & 63, ntk = c >> 6;
    int nt = ntk % 12, kc = ntk / 12;
    int n = nt * 16 + (lane & 15);
    int col = kc * 32 + (lane >> 4) * 8;
    const float* src = (n < 64) ? Wk + n * 1024
                     : (n < 128) ? Wq + (n - 64) * 1024
                                 : Wv + (n - 128) * 1024;
    float4 a = *(const float4*)(src + col);
    float4 b = *(const float4*)(src + col + 4);
    bf16x8 o;
    o[0] = f2bf(a.x); o[1] = f2bf(a.y); o[2] = f2bf(a.z); o[3] = f2bf(a.w);
    o[4] = f2bf(b.x); o[5] = f2bf(b.y); o[6] = f2bf(b.z); o[7] = f2bf(b.w);
    *(bf16x8*)(W2 + (size_t)c * 8) = o;
}

// ---------- K2: QKV projection — fully LDS-staged, triple-buffered ----------
// Session-best artifact (R6: 131.8us e2e, passed). Stage x AND W2 per K-step
// via global_load_lds, 3 buffers, prefetch distance 2, counted vmcnt(10)
// (T4, never 0 mid-loop). W2 lines fetched once per BLOCK. Residual qkv gap
// (~36us vs ~10-15us model, all pipes idle, invariant across 4 structures)
// is unexplained intra-kernel; leading hypothesis is environment-level
// (post-fill clock state / per-dispatch fixed cost — R8/R9 fusion test was
// confounded by register spills, VGPR 84 + 20MB spill traffic).
__global__ __launch_bounds__(512) void qkv_proj(const float* __restrict__ x,
                                                const short* __restrict__ W2,
                                                short* __restrict__ Qb,
                                                short* __restrict__ Kb,
                                                short* __restrict__ Vt) {
    __shared__ __align__(16) char xbuf[3][16384];   // [buf][64 rows][256 B], XOR-swizzled
    __shared__ __align__(16) char wbuf[3][24576];   // [buf][2 kc][12 nt][64 lane][16 B]
    int tid = threadIdx.x, wid = tid >> 6, lane = tid & 63;
    int l15 = lane & 15, quad = lane >> 4;
    int mgrp = wid >> 2;                  // m-tiles mgrp*32 .. +31
    int ngrp = wid & 3;                   // nt = ngrp*3 + j
    int m0 = blockIdx.x * 64;             // grid 256

    f32x4 acc[2][3];                      // [mt][j]
#pragma unroll
    for (int i = 0; i < 2; ++i)
#pragma unroll
        for (int j = 0; j < 3; ++j) acc[i][j] = f32x4{0.f, 0.f, 0.f, 0.f};

    // x stage: 2 instrs/wave, 4 rows each; source pre-swizzled by (row&7)<<4 (G21)
    int xr0 = wid * 8 + quad;             // rows wid*8 .. +3   (xr0&7 == quad)
    int xr1 = wid * 8 + 4 + quad;         // rows wid*8+4 .. +7 (xr1&7 == 4+quad)
    const char* xs0 = (const char*)x + ((size_t)(m0 + xr0) << 12)
                    + ((l15 * 16) ^ ((xr0 & 7) << 4));
    const char* xs1 = (const char*)x + ((size_t)(m0 + xr1) << 12)
                    + ((l15 * 16) ^ ((xr1 & 7) << 4));
    // W2 stage: 3 instrs/wave (chunks wid*3+j of 24), already frag-ordered -> linear
    const char* wsrc = (const char*)W2 + (size_t)(wid * 3) * 1024 + lane * 16;

#define STAGE(bsel, t) do { \
        gload_lds16(xs0 + (t) * 256, &xbuf[bsel][wid * 2048]);                      \
        gload_lds16(xs1 + (t) * 256, &xbuf[bsel][wid * 2048 + 1024]);               \
        gload_lds16(wsrc + (size_t)(t) * 24576,        &wbuf[bsel][wid * 3072]);        \
        gload_lds16(wsrc + (size_t)(t) * 24576 + 1024, &wbuf[bsel][wid * 3072 + 1024]); \
        gload_lds16(wsrc + (size_t)(t) * 24576 + 2048, &wbuf[bsel][wid * 3072 + 2048]); } while (0)

    STAGE(0, 0);                          // prologue: 2 tiles in flight
    STAGE(1, 1);
    int sw = (l15 & 7) << 4;              // A-read swizzle (rows == l15 mod 8)
#pragma unroll
    for (int t = 0; t < 16; ++t) {
        if (t < 14) {
            STAGE((t + 2) % 3, t + 2);    // buf was consumed at iter t-1 (trailing barrier)
            asm volatile("s_waitcnt vmcnt(10)" ::: "memory");  // drain stage(t), keep 2 in flight
        } else if (t == 14) {
            asm volatile("s_waitcnt vmcnt(5)" ::: "memory");
        } else {
            asm volatile("s_waitcnt vmcnt(0)" ::: "memory");
        }
        __builtin_amdgcn_s_barrier();     // buf[t%3] fully staged, all waves
        __builtin_amdgcn_sched_barrier(0);

        const char* xb = xbuf[t % 3];
        const char* wb = wbuf[t % 3];
        // B-frags: 6 ds_read_b128, contiguous (conflict-free)
        bf16x8 wf[2][3];
        {
            const char* wbn = wb + (size_t)(ngrp * 3) * 1024 + lane * 16;
#pragma unroll
            for (int j = 0; j < 3; ++j) {
                wf[0][j] = *(const bf16x8*)(wbn + j * 1024);
                wf[1][j] = *(const bf16x8*)(wbn + j * 1024 + 12288);
            }
        }
        // A-frags: 8 ds_read_b128, XOR-swizzled (2-way max = free)
        bf16x8 af[2][2];
#pragma unroll
        for (int mt = 0; mt < 2; ++mt)
#pragma unroll
            for (int kk = 0; kk < 2; ++kk) {
                const char* xr = xb + (mgrp * 32 + mt * 16 + l15) * 256 + kk * 128;
                float4 a0 = *(const float4*)(xr + ((quad * 32) ^ sw));
                float4 a1 = *(const float4*)(xr + ((quad * 32 + 16) ^ sw));
                af[mt][kk] = pack4(cvt_pk_bf16(a0.x, a0.y), cvt_pk_bf16(a0.z, a0.w),
                                   cvt_pk_bf16(a1.x, a1.y), cvt_pk_bf16(a1.z, a1.w));
            }
#pragma unroll
        for (int kk = 0; kk < 2; ++kk)
#pragma unroll
            for (int j = 0; j < 3; ++j) {
                acc[0][j] = MFMA32(af[0][kk], wf[kk][j], acc[0][j]);
                acc[1][j] = MFMA32(af[1][kk], wf[kk][j], acc[1][j]);
            }
        __builtin_amdgcn_s_barrier();     // reads of buf[t%3] done -> re-stageable
    }
#undef STAGE

    // ---- epilogue: direct stores, no cross-wave reduction (verified R5/R6) ----
    int blk = blockIdx.x;
    int bb = blk >> 5;                    // batch (32 blocks of 64 rows per batch)
    int inb = blk & 31;
#pragma unroll
    for (int j = 0; j < 3; ++j) {
        int gnt = ngrp * 3 + j;           // wave-uniform
#pragma unroll
        for (int mt = 0; mt < 2; ++mt) {
            int gmt = mgrp * 2 + mt;
            f32x4 s0 = acc[mt][j];
            int row0 = m0 + gmt * 16 + quad * 4;
            if (gnt < 4) {                // K rows [m][h]
                int h = gnt * 16 + l15;
#pragma unroll
                for (int r = 0; r < 4; ++r)
                    Kb[(size_t)(row0 + r) * HD + h] = f2bf(s0[r]);
            } else if (gnt < 8) {         // Q rows, pre-scaled
                int h = (gnt - 4) * 16 + l15;
#pragma unroll
                for (int r = 0; r < 4; ++r)
                    Qb[(size_t)(row0 + r) * HD + h] = f2bf(s0[r] * QSCALE);
            } else {                      // V: [b][s/32][h][32], pos = quad*8 + half*4 + r
                int h = (gnt - 8) * 16 + l15;
                int sblk32 = inb * 2 + (gmt >> 1);
                int half = gmt & 1;
                uint2 v2;
                v2.x = cvt_pk_bf16(s0[0], s0[1]);
                v2.y = cvt_pk_bf16(s0[2], s0[3]);
                *(uint2*)(Vt + ((size_t)((bb * 64 + sblk32) * 64 + h)) * 32
                             + quad * 8 + half * 4) = v2;
            }
        }
    }
}

// ---------- K3: causal flash — 2 q-tiles/wave, transpose-free PV ----------
__global__ __launch_bounds__(256) void flash(const short* __restrict__ Qb,
                                             const short* __restrict__ Kb,
                                             const short* __restrict__ Vt,
                                             float* __restrict__ out) {
    __shared__ float Of[4][2][16][68];     // merge only (~35 KB)
    __shared__ float Ml[4][2][16];
    int tid = threadIdx.x, wave = tid >> 6, lane = tid & 63;
    int l15 = lane & 15, quad = lane >> 4;
    // CU-balance: CU c gets q32 = {g, 63-g} across the 2 rounds
    int i = blockIdx.x;                    // grid 512
    int round = i >> 8, s = i & 255;
    int b = s & 7;
    int g32 = s >> 3;
    int q32 = round ? 63 - g32 : g32;
    int tq0 = q32 * 32;
    size_t bT = (size_t)b * TB;

    const short* qr0 = Qb + (bT + tq0 + l15) * HD;        // pre-scaled
    const short* qr1 = Qb + (bT + tq0 + 16 + l15) * HD;
    bf16x8 qf00 = *(const bf16x8*)(qr0 + quad * 8);
    bf16x8 qf01 = *(const bf16x8*)(qr0 + 32 + quad * 8);
    bf16x8 qf10 = *(const bf16x8*)(qr1 + quad * 8);
    bf16x8 qf11 = *(const bf16x8*)(qr1 + 32 + quad * 8);

    bf16x4 ones4;
#pragma unroll
    for (int j = 0; j < 4; ++j) ones4[j] = (short)0x3F80;

    f32x4 accO0[4], accO1[4];
#pragma unroll
    for (int k = 0; k < 4; ++k) { accO0[k] = f32x4{0.f,0.f,0.f,0.f}; accO1[k] = f32x4{0.f,0.f,0.f,0.f}; }
    f32x4 accL0 = f32x4{0.f,0.f,0.f,0.f}, accL1 = f32x4{0.f,0.f,0.f,0.f};

    int ntiles = (tq0 + 95) >> 6;          // keys needed: tq0+32
    const short* kbase = Kb + bT * HD;
    const short* vtb = Vt + (size_t)b * 131072;  // [64 sblk32][64 h][32]

    int myt = wave;
    if (myt < ntiles) {
        bf16x8 kf[8];
        {
            const short* kr = kbase + (size_t)(myt * 64 + l15) * HD + quad * 8;
#pragma unroll
            for (int st = 0; st < 4; ++st) {
                kf[st * 2]     = *(const bf16x8*)(kr + (size_t)st * 16 * HD);
                kf[st * 2 + 1] = *(const bf16x8*)(kr + (size_t)st * 16 * HD + 32);
            }
        }
        for (; myt < ntiles; myt += 4) {
            int s0 = myt * 64;
            // V A-frags: one 16B load serves two 16-s groups (lo/hi halves)
            bf16x8 vf8[8];                 // [sb2*4 + ht]
#pragma unroll
            for (int sb2 = 0; sb2 < 2; ++sb2)
#pragma unroll
                for (int ht = 0; ht < 4; ++ht)
                    vf8[sb2 * 4 + ht] = *(const bf16x8*)(
                        vtb + ((size_t)(((s0 >> 5) + sb2) * 64 + ht * 16 + l15)) * 32 + quad * 8);
            // S^T = mfma(A=K, B=Q) for both q-tiles (K shared)
            f32x4 sv0[4], sv1[4];
            __builtin_amdgcn_s_setprio(1);     // T5
#pragma unroll
            for (int st = 0; st < 4; ++st) {
                f32x4 t0 = f32x4{0.f,0.f,0.f,0.f}, t1 = f32x4{0.f,0.f,0.f,0.f};
                t0 = MFMA32(kf[st * 2], qf00, t0);
                t0 = MFMA32(kf[st * 2 + 1], qf01, t0);
                t1 = MFMA32(kf[st * 2], qf10, t1);
                t1 = MFMA32(kf[st * 2 + 1], qf11, t1);
                sv0[st] = t0; sv1[st] = t1;
            }
            __builtin_amdgcn_s_setprio(0);
            // prefetch next K tile
            if (myt + 4 < ntiles) {
                const short* kr = kbase + (size_t)(s0 + 256 + l15) * HD + quad * 8;
#pragma unroll
                for (int st = 0; st < 4; ++st) {
                    kf[st * 2]     = *(const bf16x8*)(kr + (size_t)st * 16 * HD);
                    kf[st * 2 + 1] = *(const bf16x8*)(kr + (size_t)st * 16 * HD + 32);
                }
            }
            // exp2 -> P^T B-frags. Wave-uniform split: ~94% of tiles are fully
            // below the diagonal for both q-tiles -> no per-element masking at all.
            bf16x4 pk0[4], pk1[4];
            if (s0 + 63 <= tq0) {          // full tile: exp2 + cvt_pk only
#pragma unroll
                for (int st = 0; st < 4; ++st) {
                    unsigned w00 = cvt_pk_bf16(__builtin_amdgcn_exp2f(sv0[st][0]),
                                               __builtin_amdgcn_exp2f(sv0[st][1]));
                    unsigned w01 = cvt_pk_bf16(__builtin_amdgcn_exp2f(sv0[st][2]),
                                               __builtin_amdgcn_exp2f(sv0[st][3]));
                    unsigned w10 = cvt_pk_bf16(__builtin_amdgcn_exp2f(sv1[st][0]),
                                               __builtin_amdgcn_exp2f(sv1[st][1]));
                    unsigned w11 = cvt_pk_bf16(__builtin_amdgcn_exp2f(sv1[st][2]),
                                               __builtin_amdgcn_exp2f(sv1[st][3]));
                    pk0[st] = pack2(w00, w01);
                    pk1[st] = pack2(w10, w11);
                }
            } else {                       // diagonal tile: per-element causal mask
                int t0g = tq0 + l15, t1g = tq0 + 16 + l15;
#pragma unroll
                for (int st = 0; st < 4; ++st) {
                    bool full0 = (s0 + st * 16 + 15 <= tq0);
                    bool full1 = (s0 + st * 16 + 15 <= tq0 + 16);
                    int sb = s0 + st * 16 + quad * 4;
                    float a0 = (full0 || sb + 0 <= t0g) ? __builtin_amdgcn_exp2f(sv0[st][0]) : 0.f;
                    float a1 = (full0 || sb + 1 <= t0g) ? __builtin_amdgcn_exp2f(sv0[st][1]) : 0.f;
                    float a2 = (full0 || sb + 2 <= t0g) ? __builtin_amdgcn_exp2f(sv0[st][2]) : 0.f;
                    float a3 = (full0 || sb + 3 <= t0g) ? __builtin_amdgcn_exp2f(sv0[st][3]) : 0.f;
                    float c0 = (full1 || sb + 0 <= t1g) ? __builtin_amdgcn_exp2f(sv1[st][0]) : 0.f;
                    float c1 = (full1 || sb + 1 <= t1g) ? __builtin_amdgcn_exp2f(sv1[st][1]) : 0.f;
                    float c2 = (full1 || sb + 2 <= t1g) ? __builtin_amdgcn_exp2f(sv1[st][2]) : 0.f;
                    float c3 = (full1 || sb + 3 <= t1g) ? __builtin_amdgcn_exp2f(sv1[st][3]) : 0.f;
                    pk0[st] = pack2(cvt_pk_bf16(a0, a1), cvt_pk_bf16(a2, a3));
                    pk1[st] = pack2(cvt_pk_bf16(c0, c1), cvt_pk_bf16(c2, c3));
                }
            }
            // O^T += V^T x P^T (V shared); rowsum via ones-A
            __builtin_amdgcn_s_setprio(1);
#pragma unroll
            for (int g = 0; g < 4; ++g) {
                accL0 = MFMA16(ones4, pk0[g], accL0);
                accL1 = MFMA16(ones4, pk1[g], accL1);
#pragma unroll
                for (int ht = 0; ht < 4; ++ht) {
                    bf16x8 v = vf8[(g >> 1) * 4 + ht];
                    bf16x4 va;
                    if (g & 1) { va[0] = v[4]; va[1] = v[5]; va[2] = v[6]; va[3] = v[7]; }
                    else       { va[0] = v[0]; va[1] = v[1]; va[2] = v[2]; va[3] = v[3]; }
                    accO0[ht] = MFMA16(va, pk0[g], accO0[ht]);
                    accO1[ht] = MFMA16(va, pk1[g], accO1[ht]);
                }
            }
            __builtin_amdgcn_s_setprio(0);
        }
    }

    // ---- merge 4 partials per q-tile ----
#pragma unroll
    for (int ht = 0; ht < 4; ++ht) {
        float4 o0, o1;
        o0.x = accO0[ht][0]; o0.y = accO0[ht][1]; o0.z = accO0[ht][2]; o0.w = accO0[ht][3];
        o1.x = accO1[ht][0]; o1.y = accO1[ht][1]; o1.z = accO1[ht][2]; o1.w = accO1[ht][3];
        *(float4*)&Of[wave][0][l15][ht * 16 + quad * 4] = o0;
        *(float4*)&Of[wave][1][l15][ht * 16 + quad * 4] = o1;
    }
    if (quad == 0) { Ml[wave][0][l15] = accL0[0]; Ml[wave][1][l15] = accL1[0]; }
    __syncthreads();

    int row = tid >> 4, c4 = (tid & 15) * 4;
#pragma unroll
    for (int qt = 0; qt < 2; ++qt) {
        float L = Ml[0][qt][row] + Ml[1][qt][row] + Ml[2][qt][row] + Ml[3][qt][row];
        float inv = 1.0f / L;
        float4 p0 = *(const float4*)&Of[0][qt][row][c4];
        float4 p1 = *(const float4*)&Of[1][qt][row][c4];
        float4 p2 = *(const float4*)&Of[2][qt][row][c4];
        float4 p3 = *(const float4*)&Of[3][qt][row][c4];
        float4 o;
        o.x = (p0.x + p1.x + p2.x + p3.x) * inv;
        o.y = (p0.y + p1.y + p2.y + p3.y) * inv;
        o.z = (p0.z + p1.z + p2.z + p3.z) * inv;
        o.w = (p0.w + p1.w + p2.w + p3.w) * inv;
        *(float4*)(out + (bT + tq0 + qt * 16 + row) * HD + c4) = o;
    }
}

extern "C" void kernel_launch(void* const* d_in, const int* in_sizes, int n_in,
                              void* d_out, int out_size, void* d_ws, size_t ws_size,
                              hipStream_t stream) {
    const float* x  = (const float*)d_in[0];
    const float* Wk = (const float*)d_in[1];
    const float* Wq = (const float*)d_in[2];
    const float* Wv = (const float*)d_in[3];
    float* out = (float*)d_out;

    short* W2 = (short*)d_ws;                // 192*1024 bf16 (frag-packed)
    short* Qb = W2 + 192 * 1024;             // [BT][64], pre-scaled
    short* Kb = Qb + (size_t)BT * HD;        // [BT][64]
    short* Vt = Kb + (size_t)BT * HD;        // [B][64 sblk32][64 h][32]

    wpack<<<96, 256, 0, stream>>>(Wk, Wq, Wv, W2);
    qkv_proj<<<256, 512, 0, stream>>>(x, W2, Qb, Kb, Vt);
    flash<<<512, 256, 0, stream>>>(Qb, Kb, Vt, out);
}

// Round 13
// 130.052 us; speedup vs baseline: 2.8396x; 1.0109x over previous
//
#include <hip/hip_runtime.h>

// Problem constants (B=8, T=2048, C=1024, H=64)
#define TB 2048
#define NB 8
#define CEMB 1024
#define HD 64
#define BT (NB*TB)
// Q pre-scale: 1/sqrt(1024) * log2(e) — softmax in exp2 domain, no online max
#define QSCALE 0.04508422f

typedef __attribute__((ext_vector_type(8))) short bf16x8;
typedef __attribute__((ext_vector_type(4))) short bf16x4;
typedef __attribute__((ext_vector_type(4))) float f32x4;

#define MFMA32(a, b, c) __builtin_amdgcn_mfma_f32_16x16x32_bf16(a, b, c, 0, 0, 0)
// no __has_builtin guard — returns false on the HOST pass (R8 failure)
#define MFMA16(a, b, c) __builtin_amdgcn_mfma_f32_16x16x16bf16_1k(a, b, c, 0, 0, 0)

__device__ inline short f2bf(float f) {
    union { float f; unsigned u; } v; v.f = f;
    unsigned r = v.u + 0x7fffu + ((v.u >> 16) & 1u);   // RNE
    return (short)(r >> 16);
}
__device__ inline float bf2f(short s) {
    union { unsigned u; float f; } v; v.u = ((unsigned)(unsigned short)s) << 16;
    return v.f;
}
// HW packed f32->bf16 RNE: 1 op per pair
__device__ inline unsigned cvt_pk_bf16(float a, float b) {
    unsigned r;
    asm("v_cvt_pk_bf16_f32 %0, %1, %2" : "=v"(r) : "v"(a), "v"(b));
    return r;
}
__device__ inline bf16x4 pack2(unsigned w0, unsigned w1) {
    union { unsigned u[2]; bf16x4 v; } c; c.u[0] = w0; c.u[1] = w1; return c.v;
}
__device__ inline bf16x8 pack4(unsigned w0, unsigned w1, unsigned w2, unsigned w3) {
    union { unsigned u[4]; bf16x8 v; } c;
    c.u[0] = w0; c.u[1] = w1; c.u[2] = w2; c.u[3] = w3; return c.v;
}
// async global->LDS 16B (dest = wave-uniform base + lane*16; src per-lane)
__device__ inline void gload_lds16(const void* g, void* l) {
    __builtin_amdgcn_global_load_lds((const __attribute__((address_space(1))) void*)g,
                                     (__attribute__((address_space(3))) void*)l, 16, 0, 0);
}

// ---------- K1: pack [Wk;Wq;Wv] into MFMA B-frag order, bf16 ----------
__global__ __launch_bounds__(256) void wpack(const float* __restrict__ Wk,
                                             const float* __restrict__ Wq,
                                             const float* __restrict__ Wv,
                                             short* __restrict__ W2) {
    int c = blockIdx.x * 256 + threadIdx.x;          // 96 blocks
    int lane = c & 63, ntk = c >> 6;
    int nt = ntk % 12, kc = ntk / 12;
    int n = nt * 16 + (lane & 15);
    int col = kc * 32 + (lane >> 4) * 8;
    const float* src = (n < 64) ? Wk + n * 1024
                     : (n < 128) ? Wq + (n - 64) * 1024
                                 : Wv + (n - 128) * 1024;
    float4 a = *(const float4*)(src + col);
    float4 b = *(const float4*)(src + col + 4);
    bf16x8 o;
    o[0] = f2bf(a.x); o[1] = f2bf(a.y); o[2] = f2bf(a.z); o[3] = f2bf(a.w);
    o[4] = f2bf(b.x); o[5] = f2bf(b.y); o[6] = f2bf(b.z); o[7] = f2bf(b.w);
    *(bf16x8*)(W2 + (size_t)c * 8) = o;
}

// ---------- K2: QKV projection — fully LDS-staged, triple-buffered ----------
// Session-best artifact (R6: 131.8us, R12: 131.5us — reproducible). Stage x
// AND W2 per K-step via global_load_lds, 3 buffers, prefetch distance 2,
// counted vmcnt(10) (T4, never 0 mid-loop). W2 lines fetched once per BLOCK.
// Residual qkv gap (~36us vs ~10-15us model, all pipes idle, invariant across
// 4 structures) is environment-level per the evidence: fill-dominated duty
// cycle parks SCLK / per-dispatch fixed cost. The R8/R9 single-dispatch
// fusion probe passed correctness but spilled (VGPR 84, +20MB scratch) ->
// 317us; a noinline-phase retry is the one remaining experiment.
__global__ __launch_bounds__(512) void qkv_proj(const float* __restrict__ x,
                                                const short* __restrict__ W2,
                                                short* __restrict__ Qb,
                                                short* __restrict__ Kb,
                                                short* __restrict__ Vt) {
    __shared__ __align__(16) char xbuf[3][16384];   // [buf][64 rows][256 B], XOR-swizzled
    __shared__ __align__(16) char wbuf[3][24576];   // [buf][2 kc][12 nt][64 lane][16 B]
    int tid = threadIdx.x, wid = tid >> 6, lane = tid & 63;
    int l15 = lane & 15, quad = lane >> 4;
    int mgrp = wid >> 2;                  // m-tiles mgrp*32 .. +31
    int ngrp = wid & 3;                   // nt = ngrp*3 + j
    int m0 = blockIdx.x * 64;             // grid 256

    f32x4 acc[2][3];                      // [mt][j]
#pragma unroll
    for (int i = 0; i < 2; ++i)
#pragma unroll
        for (int j = 0; j < 3; ++j) acc[i][j] = f32x4{0.f, 0.f, 0.f, 0.f};

    // x stage: 2 instrs/wave, 4 rows each; source pre-swizzled by (row&7)<<4 (G21)
    int xr0 = wid * 8 + quad;             // rows wid*8 .. +3   (xr0&7 == quad)
    int xr1 = wid * 8 + 4 + quad;         // rows wid*8+4 .. +7 (xr1&7 == 4+quad)
    const char* xs0 = (const char*)x + ((size_t)(m0 + xr0) << 12)
                    + ((l15 * 16) ^ ((xr0 & 7) << 4));
    const char* xs1 = (const char*)x + ((size_t)(m0 + xr1) << 12)
                    + ((l15 * 16) ^ ((xr1 & 7) << 4));
    // W2 stage: 3 instrs/wave (chunks wid*3+j of 24), already frag-ordered -> linear
    const char* wsrc = (const char*)W2 + (size_t)(wid * 3) * 1024 + lane * 16;

#define STAGE(bsel, t) do { \
        gload_lds16(xs0 + (t) * 256, &xbuf[bsel][wid * 2048]);                      \
        gload_lds16(xs1 + (t) * 256, &xbuf[bsel][wid * 2048 + 1024]);               \
        gload_lds16(wsrc + (size_t)(t) * 24576,        &wbuf[bsel][wid * 3072]);        \
        gload_lds16(wsrc + (size_t)(t) * 24576 + 1024, &wbuf[bsel][wid * 3072 + 1024]); \
        gload_lds16(wsrc + (size_t)(t) * 24576 + 2048, &wbuf[bsel][wid * 3072 + 2048]); } while (0)

    STAGE(0, 0);                          // prologue: 2 tiles in flight
    STAGE(1, 1);
    int sw = (l15 & 7) << 4;              // A-read swizzle (rows == l15 mod 8)
#pragma unroll
    for (int t = 0; t < 16; ++t) {
        if (t < 14) {
            STAGE((t + 2) % 3, t + 2);    // buf was consumed at iter t-1 (trailing barrier)
            asm volatile("s_waitcnt vmcnt(10)" ::: "memory");  // drain stage(t), keep 2 in flight
        } else if (t == 14) {
            asm volatile("s_waitcnt vmcnt(5)" ::: "memory");
        } else {
            asm volatile("s_waitcnt vmcnt(0)" ::: "memory");
        }
        __builtin_amdgcn_s_barrier();     // buf[t%3] fully staged, all waves
        __builtin_amdgcn_sched_barrier(0);

        const char* xb = xbuf[t % 3];
        const char* wb = wbuf[t % 3];
        // B-frags: 6 ds_read_b128, contiguous (conflict-free)
        bf16x8 wf[2][3];
        {
            const char* wbn = wb + (size_t)(ngrp * 3) * 1024 + lane * 16;
#pragma unroll
            for (int j = 0; j < 3; ++j) {
                wf[0][j] = *(const bf16x8*)(wbn + j * 1024);
                wf[1][j] = *(const bf16x8*)(wbn + j * 1024 + 12288);
            }
        }
        // A-frags: 8 ds_read_b128, XOR-swizzled (2-way max = free)
        bf16x8 af[2][2];
#pragma unroll
        for (int mt = 0; mt < 2; ++mt)
#pragma unroll
            for (int kk = 0; kk < 2; ++kk) {
                const char* xr = xb + (mgrp * 32 + mt * 16 + l15) * 256 + kk * 128;
                float4 a0 = *(const float4*)(xr + ((quad * 32) ^ sw));
                float4 a1 = *(const float4*)(xr + ((quad * 32 + 16) ^ sw));
                af[mt][kk] = pack4(cvt_pk_bf16(a0.x, a0.y), cvt_pk_bf16(a0.z, a0.w),
                                   cvt_pk_bf16(a1.x, a1.y), cvt_pk_bf16(a1.z, a1.w));
            }
#pragma unroll
        for (int kk = 0; kk < 2; ++kk)
#pragma unroll
            for (int j = 0; j < 3; ++j) {
                acc[0][j] = MFMA32(af[0][kk], wf[kk][j], acc[0][j]);
                acc[1][j] = MFMA32(af[1][kk], wf[kk][j], acc[1][j]);
            }
        __builtin_amdgcn_s_barrier();     // reads of buf[t%3] done -> re-stageable
    }
#undef STAGE

    // ---- epilogue: direct stores, no cross-wave reduction (verified R5/R6) ----
    int blk = blockIdx.x;
    int bb = blk >> 5;                    // batch (32 blocks of 64 rows per batch)
    int inb = blk & 31;
#pragma unroll
    for (int j = 0; j < 3; ++j) {
        int gnt = ngrp * 3 + j;           // wave-uniform
#pragma unroll
        for (int mt = 0; mt < 2; ++mt) {
            int gmt = mgrp * 2 + mt;
            f32x4 s0 = acc[mt][j];
            int row0 = m0 + gmt * 16 + quad * 4;
            if (gnt < 4) {                // K rows [m][h]
                int h = gnt * 16 + l15;
#pragma unroll
                for (int r = 0; r < 4; ++r)
                    Kb[(size_t)(row0 + r) * HD + h] = f2bf(s0[r]);
            } else if (gnt < 8) {         // Q rows, pre-scaled
                int h = (gnt - 4) * 16 + l15;
#pragma unroll
                for (int r = 0; r < 4; ++r)
                    Qb[(size_t)(row0 + r) * HD + h] = f2bf(s0[r] * QSCALE);
            } else {                      // V: [b][s/32][h][32], pos = quad*8 + half*4 + r
                int h = (gnt - 8) * 16 + l15;
                int sblk32 = inb * 2 + (gmt >> 1);
                int half = gmt & 1;
                uint2 v2;
                v2.x = cvt_pk_bf16(s0[0], s0[1]);
                v2.y = cvt_pk_bf16(s0[2], s0[3]);
                *(uint2*)(Vt + ((size_t)((bb * 64 + sblk32) * 64 + h)) * 32
                             + quad * 8 + half * 4) = v2;
            }
        }
    }
}

// ---------- K3: causal flash — 2 q-tiles/wave, transpose-free PV ----------
__global__ __launch_bounds__(256) void flash(const short* __restrict__ Qb,
                                             const short* __restrict__ Kb,
                                             const short* __restrict__ Vt,
                                             float* __restrict__ out) {
    __shared__ float Of[4][2][16][68];     // merge only (~35 KB)
    __shared__ float Ml[4][2][16];
    int tid = threadIdx.x, wave = tid >> 6, lane = tid & 63;
    int l15 = lane & 15, quad = lane >> 4;
    // CU-balance: CU c gets q32 = {g, 63-g} across the 2 rounds
    int i = blockIdx.x;                    // grid 512
    int round = i >> 8, s = i & 255;
    int b = s & 7;
    int g32 = s >> 3;
    int q32 = round ? 63 - g32 : g32;
    int tq0 = q32 * 32;
    size_t bT = (size_t)b * TB;

    const short* qr0 = Qb + (bT + tq0 + l15) * HD;        // pre-scaled
    const short* qr1 = Qb + (bT + tq0 + 16 + l15) * HD;
    bf16x8 qf00 = *(const bf16x8*)(qr0 + quad * 8);
    bf16x8 qf01 = *(const bf16x8*)(qr0 + 32 + quad * 8);
    bf16x8 qf10 = *(const bf16x8*)(qr1 + quad * 8);
    bf16x8 qf11 = *(const bf16x8*)(qr1 + 32 + quad * 8);

    bf16x4 ones4;
#pragma unroll
    for (int j = 0; j < 4; ++j) ones4[j] = (short)0x3F80;

    f32x4 accO0[4], accO1[4];
#pragma unroll
    for (int k = 0; k < 4; ++k) { accO0[k] = f32x4{0.f,0.f,0.f,0.f}; accO1[k] = f32x4{0.f,0.f,0.f,0.f}; }
    f32x4 accL0 = f32x4{0.f,0.f,0.f,0.f}, accL1 = f32x4{0.f,0.f,0.f,0.f};

    int ntiles = (tq0 + 95) >> 6;          // keys needed: tq0+32
    const short* kbase = Kb + bT * HD;
    const short* vtb = Vt + (size_t)b * 131072;  // [64 sblk32][64 h][32]

    int myt = wave;
    if (myt < ntiles) {
        bf16x8 kf[8];
        {
            const short* kr = kbase + (size_t)(myt * 64 + l15) * HD + quad * 8;
#pragma unroll
            for (int st = 0; st < 4; ++st) {
                kf[st * 2]     = *(const bf16x8*)(kr + (size_t)st * 16 * HD);
                kf[st * 2 + 1] = *(const bf16x8*)(kr + (size_t)st * 16 * HD + 32);
            }
        }
        for (; myt < ntiles; myt += 4) {
            int s0 = myt * 64;
            // V A-frags: one 16B load serves two 16-s groups (lo/hi halves)
            bf16x8 vf8[8];                 // [sb2*4 + ht]
#pragma unroll
            for (int sb2 = 0; sb2 < 2; ++sb2)
#pragma unroll
                for (int ht = 0; ht < 4; ++ht)
                    vf8[sb2 * 4 + ht] = *(const bf16x8*)(
                        vtb + ((size_t)(((s0 >> 5) + sb2) * 64 + ht * 16 + l15)) * 32 + quad * 8);
            // S^T = mfma(A=K, B=Q) for both q-tiles (K shared)
            f32x4 sv0[4], sv1[4];
            __builtin_amdgcn_s_setprio(1);     // T5
#pragma unroll
            for (int st = 0; st < 4; ++st) {
                f32x4 t0 = f32x4{0.f,0.f,0.f,0.f}, t1 = f32x4{0.f,0.f,0.f,0.f};
                t0 = MFMA32(kf[st * 2], qf00, t0);
                t0 = MFMA32(kf[st * 2 + 1], qf01, t0);
                t1 = MFMA32(kf[st * 2], qf10, t1);
                t1 = MFMA32(kf[st * 2 + 1], qf11, t1);
                sv0[st] = t0; sv1[st] = t1;
            }
            __builtin_amdgcn_s_setprio(0);
            // prefetch next K tile
            if (myt + 4 < ntiles) {
                const short* kr = kbase + (size_t)(s0 + 256 + l15) * HD + quad * 8;
#pragma unroll
                for (int st = 0; st < 4; ++st) {
                    kf[st * 2]     = *(const bf16x8*)(kr + (size_t)st * 16 * HD);
                    kf[st * 2 + 1] = *(const bf16x8*)(kr + (size_t)st * 16 * HD + 32);
                }
            }
            // exp2 -> P^T B-frags. Wave-uniform split: ~94% of tiles are fully
            // below the diagonal for both q-tiles -> no per-element masking at all.
            bf16x4 pk0[4], pk1[4];
            if (s0 + 63 <= tq0) {          // full tile: exp2 + cvt_pk only
#pragma unroll
                for (int st = 0; st < 4; ++st) {
                    unsigned w00 = cvt_pk_bf16(__builtin_amdgcn_exp2f(sv0[st][0]),
                                               __builtin_amdgcn_exp2f(sv0[st][1]));
                    unsigned w01 = cvt_pk_bf16(__builtin_amdgcn_exp2f(sv0[st][2]),
                                               __builtin_amdgcn_exp2f(sv0[st][3]));
                    unsigned w10 = cvt_pk_bf16(__builtin_amdgcn_exp2f(sv1[st][0]),
                                               __builtin_amdgcn_exp2f(sv1[st][1]));
                    unsigned w11 = cvt_pk_bf16(__builtin_amdgcn_exp2f(sv1[st][2]),
                                               __builtin_amdgcn_exp2f(sv1[st][3]));
                    pk0[st] = pack2(w00, w01);
                    pk1[st] = pack2(w10, w11);
                }
            } else {                       // diagonal tile: per-element causal mask
                int t0g = tq0 + l15, t1g = tq0 + 16 + l15;
#pragma unroll
                for (int st = 0; st < 4; ++st) {
                    bool full0 = (s0 + st * 16 + 15 <= tq0);
                    bool full1 = (s0 + st * 16 + 15 <= tq0 + 16);
                    int sb = s0 + st * 16 + quad * 4;
                    float a0 = (full0 || sb + 0 <= t0g) ? __builtin_amdgcn_exp2f(sv0[st][0]) : 0.f;
                    float a1 = (full0 || sb + 1 <= t0g) ? __builtin_amdgcn_exp2f(sv0[st][1]) : 0.f;
                    float a2 = (full0 || sb + 2 <= t0g) ? __builtin_amdgcn_exp2f(sv0[st][2]) : 0.f;
                    float a3 = (full0 || sb + 3 <= t0g) ? __builtin_amdgcn_exp2f(sv0[st][3]) : 0.f;
                    float c0 = (full1 || sb + 0 <= t1g) ? __builtin_amdgcn_exp2f(sv1[st][0]) : 0.f;
                    float c1 = (full1 || sb + 1 <= t1g) ? __builtin_amdgcn_exp2f(sv1[st][1]) : 0.f;
                    float c2 = (full1 || sb + 2 <= t1g) ? __builtin_amdgcn_exp2f(sv1[st][2]) : 0.f;
                    float c3 = (full1 || sb + 3 <= t1g) ? __builtin_amdgcn_exp2f(sv1[st][3]) : 0.f;
                    pk0[st] = pack2(cvt_pk_bf16(a0, a1), cvt_pk_bf16(a2, a3));
                    pk1[st] = pack2(cvt_pk_bf16(c0, c1), cvt_pk_bf16(c2, c3));
                }
            }
            // O^T += V^T x P^T (V shared); rowsum via ones-A
            __builtin_amdgcn_s_setprio(1);
#pragma unroll
            for (int g = 0; g < 4; ++g) {
                accL0 = MFMA16(ones4, pk0[g], accL0);
                accL1 = MFMA16(ones4, pk1[g], accL1);
#pragma unroll
                for (int ht = 0; ht < 4; ++ht) {
                    bf16x8 v = vf8[(g >> 1) * 4 + ht];
                    bf16x4 va;
                    if (g & 1) { va[0] = v[4]; va[1] = v[5]; va[2] = v[6]; va[3] = v[7]; }
                    else       { va[0] = v[0]; va[1] = v[1]; va[2] = v[2]; va[3] = v[3]; }
                    accO0[ht] = MFMA16(va, pk0[g], accO0[ht]);
                    accO1[ht] = MFMA16(va, pk1[g], accO1[ht]);
                }
            }
            __builtin_amdgcn_s_setprio(0);
        }
    }

    // ---- merge 4 partials per q-tile ----
#pragma unroll
    for (int ht = 0; ht < 4; ++ht) {
        float4 o0, o1;
        o0.x = accO0[ht][0]; o0.y = accO0[ht][1]; o0.z = accO0[ht][2]; o0.w = accO0[ht][3];
        o1.x = accO1[ht][0]; o1.y = accO1[ht][1]; o1.z = accO1[ht][2]; o1.w = accO1[ht][3];
        *(float4*)&Of[wave][0][l15][ht * 16 + quad * 4] = o0;
        *(float4*)&Of[wave][1][l15][ht * 16 + quad * 4] = o1;
    }
    if (quad == 0) { Ml[wave][0][l15] = accL0[0]; Ml[wave][1][l15] = accL1[0]; }
    __syncthreads();

    int row = tid >> 4, c4 = (tid & 15) * 4;
#pragma unroll
    for (int qt = 0; qt < 2; ++qt) {
        float L = Ml[0][qt][row] + Ml[1][qt][row] + Ml[2][qt][row] + Ml[3][qt][row];
        float inv = 1.0f / L;
        float4 p0 = *(const float4*)&Of[0][qt][row][c4];
        float4 p1 = *(const float4*)&Of[1][qt][row][c4];
        float4 p2 = *(const float4*)&Of[2][qt][row][c4];
        float4 p3 = *(const float4*)&Of[3][qt][row][c4];
        float4 o;
        o.x = (p0.x + p1.x + p2.x + p3.x) * inv;
        o.y = (p0.y + p1.y + p2.y + p3.y) * inv;
        o.z = (p0.z + p1.z + p2.z + p3.z) * inv;
        o.w = (p0.w + p1.w + p2.w + p3.w) * inv;
        *(float4*)(out + (bT + tq0 + qt * 16 + row) * HD + c4) = o;
    }
}

extern "C" void kernel_launch(void* const* d_in, const int* in_sizes, int n_in,
                              void* d_out, int out_size, void* d_ws, size_t ws_size,
                              hipStream_t stream) {
    const float* x  = (const float*)d_in[0];
    const float* Wk = (const float*)d_in[1];
    const float* Wq = (const float*)d_in[2];
    const float* Wv = (const float*)d_in[3];
    float* out = (float*)d_out;

    short* W2 = (short*)d_ws;                // 192*1024 bf16 (frag-packed)
    short* Qb = W2 + 192 * 1024;             // [BT][64], pre-scaled
    short* Kb = Qb + (size_t)BT * HD;        // [BT][64]
    short* Vt = Kb + (size_t)BT * HD;        // [B][64 sblk32][64 h][32]

    wpack<<<96, 256, 0, stream>>>(Wk, Wq, Wv, W2);
    qkv_proj<<<256, 512, 0, stream>>>(x, W2, Qb, Kb, Vt);
    flash<<<512, 256, 0, stream>>>(Qb, Kb, Vt, out);
}